// Round 1
// baseline (68.152 us; speedup 1.0000x reference)
//
#include <hip/hip_runtime.h>

// ConsecutiveLoss: x is (4096, 8192) fp32.
// real_length[i] = nnz(row i); per_row = sum_{pos=1}^{rl-1} |x[i,pos]-x[i,pos-1]| / rl
// out = sum_{i>=1} per_row[i] / bsz
constexpr int SEQ   = 8192;
constexpr int BSZ   = 4096;
constexpr int BLOCK = 256;
constexpr int CHUNKS = SEQ / 4 / BLOCK;  // 8 float4 per thread

__global__ __launch_bounds__(BLOCK) void consec_loss_kernel(
    const float* __restrict__ x, float* __restrict__ out) {
    const int tid = threadIdx.x;
    const int row = blockIdx.x;
    const float4* x4 = reinterpret_cast<const float4*>(x) + (size_t)row * (SEQ / 4);
    const float*  xr = x + (size_t)row * SEQ;

    float4 v[CHUNKS];
    float  prev[CHUNKS];
    int cnt = 0;
    #pragma unroll
    for (int k = 0; k < CHUNKS; ++k) {
        const int j = tid + k * BLOCK;          // float4 chunk index within row
        v[k] = x4[j];                           // coalesced 16B/lane
        prev[k] = (j > 0) ? xr[4 * j - 1] : 0.0f;  // L1-hit scalar (neighbor's line)
        cnt += (v[k].x != 0.0f) + (v[k].y != 0.0f) + (v[k].z != 0.0f) + (v[k].w != 0.0f);
    }

    // block-reduce nonzero count (wave64 shuffle + LDS partials)
    #pragma unroll
    for (int off = 32; off > 0; off >>= 1) cnt += __shfl_down(cnt, off, 64);
    __shared__ int   cred[BLOCK / 64];
    __shared__ float sred[BLOCK / 64];
    const int wave = tid >> 6, lane = tid & 63;
    if (lane == 0) cred[wave] = cnt;
    __syncthreads();
    const int count = cred[0] + cred[1] + cred[2] + cred[3];

    // masked |diff| sum, entirely from registers
    float s = 0.0f;
    #pragma unroll
    for (int k = 0; k < CHUNKS; ++k) {
        const int j  = tid + k * BLOCK;
        const int p0 = 4 * j;                   // pos of v[k].x
        if (p0 >= 1 && p0     < count) s += fabsf(v[k].x - prev[k]);
        if (p0 + 1 < count)            s += fabsf(v[k].y - v[k].x);
        if (p0 + 2 < count)            s += fabsf(v[k].z - v[k].y);
        if (p0 + 3 < count)            s += fabsf(v[k].w - v[k].z);
    }
    #pragma unroll
    for (int off = 32; off > 0; off >>= 1) s += __shfl_down(s, off, 64);
    if (lane == 0) sred[wave] = s;
    __syncthreads();
    if (tid == 0) {
        const float tot = sred[0] + sred[1] + sred[2] + sred[3];
        if (row >= 1) {
            atomicAdd(out, tot / ((float)count * (float)BSZ));
        }
    }
}

extern "C" void kernel_launch(void* const* d_in, const int* in_sizes, int n_in,
                              void* d_out, int out_size, void* d_ws, size_t ws_size,
                              hipStream_t stream) {
    const float* x = (const float*)d_in[0];
    float* out = (float*)d_out;
    // d_out is poisoned once before timing and never re-poisoned; zero it every call.
    hipMemsetAsync(out, 0, sizeof(float), stream);
    consec_loss_kernel<<<dim3(BSZ), dim3(BLOCK), 0, stream>>>(x, out);
}

// Round 2
// 34.471 us; speedup vs baseline: 1.9771x; 1.9771x over previous
//
#include <hip/hip_runtime.h>

// ConsecutiveLoss: x is (4096, 8192) fp32.
// real_length[i] = nnz(row i); per_row = sum_{pos=1}^{rl-1} |x[i,pos]-x[i,pos-1]| / rl
// out = sum_{i>=1} per_row[i] / bsz
constexpr int SEQ    = 8192;
constexpr int BSZ    = 4096;
constexpr int BLOCK  = 256;
constexpr int CHUNKS = SEQ / 4 / BLOCK;  // 8 float4 per thread
constexpr int SLOTS  = 256;              // partial-sum slots to spread atomics

__global__ __launch_bounds__(BLOCK) void consec_loss_kernel(
    const float* __restrict__ x, float* __restrict__ ws) {
    const int tid = threadIdx.x;
    const int row = blockIdx.x;
    const float4* x4 = reinterpret_cast<const float4*>(x) + (size_t)row * (SEQ / 4);

    const int wave = tid >> 6, lane = tid & 63;

    __shared__ float bnd[BLOCK / 64][CHUNKS];  // each wave's lane-63 v[k].w
    __shared__ int   cred[BLOCK / 64];
    __shared__ float sred[BLOCK / 64];

    float4 v[CHUNKS];
    int cnt = 0;
    #pragma unroll
    for (int k = 0; k < CHUNKS; ++k) {
        const int j = tid + k * BLOCK;          // float4 chunk index within row
        v[k] = x4[j];                           // coalesced 16B/lane — the ONLY global reads
        cnt += (v[k].x != 0.0f) + (v[k].y != 0.0f) + (v[k].z != 0.0f) + (v[k].w != 0.0f);
        if (lane == 63) bnd[wave][k] = v[k].w;  // wave-boundary carry
    }

    // block-reduce nonzero count (wave64 shuffle + LDS partials)
    #pragma unroll
    for (int off = 32; off > 0; off >>= 1) cnt += __shfl_down(cnt, off, 64);
    if (lane == 0) cred[wave] = cnt;
    __syncthreads();
    const int count = cred[0] + cred[1] + cred[2] + cred[3];

    // masked |diff| sum; prev element comes from shuffle (in-wave) or LDS (wave boundary)
    float s = 0.0f;
    #pragma unroll
    for (int k = 0; k < CHUNKS; ++k) {
        const int j  = tid + k * BLOCK;
        const int p0 = 4 * j;                   // pos of v[k].x
        float prev = __shfl_up(v[k].w, 1, 64);  // lane l-1's last element = x[4j-1]
        if (lane == 0)
            prev = (wave > 0) ? bnd[wave - 1][k]
                              : (k > 0 ? bnd[BLOCK / 64 - 1][k - 1] : 0.0f);
        if (p0 >= 1 && p0     < count) s += fabsf(v[k].x - prev);
        if (p0 + 1 < count)            s += fabsf(v[k].y - v[k].x);
        if (p0 + 2 < count)            s += fabsf(v[k].z - v[k].y);
        if (p0 + 3 < count)            s += fabsf(v[k].w - v[k].z);
    }
    #pragma unroll
    for (int off = 32; off > 0; off >>= 1) s += __shfl_down(s, off, 64);
    if (lane == 0) sred[wave] = s;
    __syncthreads();
    if (tid == 0) {
        const float tot = sred[0] + sred[1] + sred[2] + sred[3];
        if (row >= 1) {
            atomicAdd(&ws[row & (SLOTS - 1)], tot / ((float)count * (float)BSZ));
        }
    }
}

__global__ __launch_bounds__(64) void consec_loss_finish(
    const float* __restrict__ ws, float* __restrict__ out) {
    const int lane = threadIdx.x;
    float s = ws[lane] + ws[lane + 64] + ws[lane + 128] + ws[lane + 192];
    #pragma unroll
    for (int off = 32; off > 0; off >>= 1) s += __shfl_down(s, off, 64);
    if (lane == 0) out[0] = s;
}

extern "C" void kernel_launch(void* const* d_in, const int* in_sizes, int n_in,
                              void* d_out, int out_size, void* d_ws, size_t ws_size,
                              hipStream_t stream) {
    const float* x = (const float*)d_in[0];
    float* ws  = (float*)d_ws;
    float* out = (float*)d_out;
    // ws is poisoned 0xAA once before timing and never re-poisoned; zero it every call.
    hipMemsetAsync(ws, 0, SLOTS * sizeof(float), stream);
    consec_loss_kernel<<<dim3(BSZ), dim3(BLOCK), 0, stream>>>(x, ws);
    consec_loss_finish<<<dim3(1), dim3(64), 0, stream>>>(ws, out);
}

// Round 3
// 28.696 us; speedup vs baseline: 2.3750x; 1.2013x over previous
//
#include <hip/hip_runtime.h>

// ConsecutiveLoss: x is (4096, 8192) fp32.
// real_length[i] = nnz(row i); per_row = sum_{pos=1}^{rl-1} |x[i,pos]-x[i,pos-1]| / rl
// out = sum_{i>=1} per_row[i] / bsz
constexpr int SEQ    = 8192;
constexpr int BSZ    = 4096;
constexpr int BLOCK  = 256;
constexpr int CHUNKS = SEQ / 4 / BLOCK;  // 8 float4 per thread

__global__ __launch_bounds__(BLOCK) void consec_loss_kernel(
    const float* __restrict__ x, float* __restrict__ ws) {
    const int tid = threadIdx.x;
    const int row = blockIdx.x;

    if (row == 0) {                      // row 0 is skipped by the reference
        if (tid == 0) ws[0] = 0.0f;
        return;
    }

    const float4* x4 = reinterpret_cast<const float4*>(x) + (size_t)row * (SEQ / 4);
    const int wave = tid >> 6, lane = tid & 63;

    __shared__ float bnd[BLOCK / 64][CHUNKS];  // each wave's lane-63 v[k].w
    __shared__ int   cred[BLOCK / 64];
    __shared__ float sred[BLOCK / 64];

    float4 v[CHUNKS];
    int cnt = 0;                          // wave-uniform via ballot+popcount (scalar pipe)
    #pragma unroll
    for (int k = 0; k < CHUNKS; ++k) {
        const int j = tid + k * BLOCK;    // float4 chunk index within row
        v[k] = x4[j];                     // coalesced 16B/lane — the ONLY global reads
        cnt += __popcll(__ballot(v[k].x != 0.0f));
        cnt += __popcll(__ballot(v[k].y != 0.0f));
        cnt += __popcll(__ballot(v[k].z != 0.0f));
        cnt += __popcll(__ballot(v[k].w != 0.0f));
        if (lane == 63) bnd[wave][k] = v[k].w;  // wave-boundary carry
    }
    if (lane == 0) cred[wave] = cnt;
    __syncthreads();
    const int count = cred[0] + cred[1] + cred[2] + cred[3];

    // masked |diff| sum; prev element comes from shuffle (in-wave) or LDS (wave boundary)
    float s = 0.0f;
    if (count == SEQ) {
        // fast path (no zeros in row): only the very first position lacks a diff
        #pragma unroll
        for (int k = 0; k < CHUNKS; ++k) {
            const int p0 = 4 * (tid + k * BLOCK);
            float prev = __shfl_up(v[k].w, 1, 64);
            if (lane == 0)
                prev = (wave > 0) ? bnd[wave - 1][k]
                                  : (k > 0 ? bnd[BLOCK / 64 - 1][k - 1] : 0.0f);
            if (p0 >= 1) s += fabsf(v[k].x - prev);
            s += fabsf(v[k].y - v[k].x);
            s += fabsf(v[k].z - v[k].y);
            s += fabsf(v[k].w - v[k].z);
        }
    } else {
        #pragma unroll
        for (int k = 0; k < CHUNKS; ++k) {
            const int p0 = 4 * (tid + k * BLOCK);
            float prev = __shfl_up(v[k].w, 1, 64);
            if (lane == 0)
                prev = (wave > 0) ? bnd[wave - 1][k]
                                  : (k > 0 ? bnd[BLOCK / 64 - 1][k - 1] : 0.0f);
            if (p0 >= 1 && p0     < count) s += fabsf(v[k].x - prev);
            if (p0 + 1 < count)            s += fabsf(v[k].y - v[k].x);
            if (p0 + 2 < count)            s += fabsf(v[k].z - v[k].y);
            if (p0 + 3 < count)            s += fabsf(v[k].w - v[k].z);
        }
    }
    #pragma unroll
    for (int off = 32; off > 0; off >>= 1) s += __shfl_down(s, off, 64);
    if (lane == 0) sred[wave] = s;
    __syncthreads();
    if (tid == 0) {
        const float tot = sred[0] + sred[1] + sred[2] + sred[3];
        ws[row] = tot / ((float)count * (float)BSZ);
    }
}

__global__ __launch_bounds__(BLOCK) void consec_loss_finish(
    const float* __restrict__ ws, float* __restrict__ out) {
    const int tid = threadIdx.x;
    const float4* w4 = reinterpret_cast<const float4*>(ws);
    float s = 0.0f;
    #pragma unroll
    for (int k = 0; k < BSZ / 4 / BLOCK; ++k) {  // 4 float4 per thread
        float4 f = w4[tid + k * BLOCK];
        s += (f.x + f.y) + (f.z + f.w);
    }
    #pragma unroll
    for (int off = 32; off > 0; off >>= 1) s += __shfl_down(s, off, 64);
    __shared__ float sred[BLOCK / 64];
    const int wave = tid >> 6, lane = tid & 63;
    if (lane == 0) sred[wave] = s;
    __syncthreads();
    if (tid == 0) out[0] = sred[0] + sred[1] + sred[2] + sred[3];
}

extern "C" void kernel_launch(void* const* d_in, const int* in_sizes, int n_in,
                              void* d_out, int out_size, void* d_ws, size_t ws_size,
                              hipStream_t stream) {
    const float* x = (const float*)d_in[0];
    float* ws  = (float*)d_ws;   // 4096 per-row partials; every slot written every call
    float* out = (float*)d_out;
    consec_loss_kernel<<<dim3(BSZ), dim3(BLOCK), 0, stream>>>(x, ws);
    consec_loss_finish<<<dim3(1), dim3(BLOCK), 0, stream>>>(ws, out);
}

// Round 4
// 28.005 us; speedup vs baseline: 2.4335x; 1.0247x over previous
//
#include <hip/hip_runtime.h>

// ConsecutiveLoss: x is (4096, 8192) fp32.
// real_length[i] = nnz(row i); per_row = sum_{pos=1}^{rl-1} |x[i,pos]-x[i,pos-1]| / rl
// out = sum_{i>=1} per_row[i] / bsz
constexpr int SEQ    = 8192;
constexpr int BSZ    = 4096;
constexpr int BLOCK  = 256;
constexpr int CHUNKS = SEQ / 4 / BLOCK;  // 8 float4 per thread

__global__ __launch_bounds__(BLOCK) void consec_loss_kernel(
    const float* __restrict__ x, float* __restrict__ ws) {
    const int tid = threadIdx.x;
    const int row = blockIdx.x;

    if (row == 0) {                      // row 0 is skipped by the reference
        if (tid == 0) ws[0] = 0.0f;
        return;
    }

    const float4* x4 = reinterpret_cast<const float4*>(x) + (size_t)row * (SEQ / 4);
    const int wave = tid >> 6, lane = tid & 63;

    __shared__ float bnd[BLOCK / 64][CHUNKS];  // each wave's lane-63 v[k].w
    __shared__ int   cred[BLOCK / 64];
    __shared__ float sred[BLOCK / 64];

    // ---- streaming phase: loads + ballots + speculative (unmasked) diffs ----
    // All diff VALU that doesn't need cross-wave data happens here, overlapped
    // with the vmcnt waits of later chunks. Only lane-0 boundary terms and the
    // (never-taken for dense rows) masked path are deferred past the barrier.
    float4 v[CHUNKS];
    float  s = 0.0f;                      // speculative unmasked |diff| sum
    int    cnt = 0;                       // wave-uniform via ballot (scalar pipe)
    #pragma unroll
    for (int k = 0; k < CHUNKS; ++k) {
        const int j = tid + k * BLOCK;    // float4 chunk index within row
        v[k] = x4[j];                     // coalesced 16B/lane — the ONLY global reads
        cnt += __popcll(__ballot(v[k].x != 0.0f));
        cnt += __popcll(__ballot(v[k].y != 0.0f));
        cnt += __popcll(__ballot(v[k].z != 0.0f));
        cnt += __popcll(__ballot(v[k].w != 0.0f));
        if (lane == 63) bnd[wave][k] = v[k].w;  // wave-boundary carry
        const float prev = __shfl_up(v[k].w, 1, 64);
        if (lane > 0) s += fabsf(v[k].x - prev);   // lanes 1..63 carry in-wave
        s += fabsf(v[k].y - v[k].x);
        s += fabsf(v[k].z - v[k].y);
        s += fabsf(v[k].w - v[k].z);
    }
    if (lane == 0) cred[wave] = cnt;
    __syncthreads();
    const int count = cred[0] + cred[1] + cred[2] + cred[3];

    if (count == SEQ) {
        // dense row (common case): speculative sum is exact; add the 8 (or 7)
        // wave-boundary diffs only lane 0 couldn't compute in-stream.
        if (lane == 0) {
            #pragma unroll
            for (int k = 0; k < CHUNKS; ++k) {
                if (wave > 0)      s += fabsf(v[k].x - bnd[wave - 1][k]);
                else if (k > 0)    s += fabsf(v[k].x - bnd[BLOCK / 64 - 1][k - 1]);
                // wave 0, k 0: position 0 has no predecessor
            }
        }
    } else {
        // masked path (row has zeros): full recompute from register-resident v[]
        s = 0.0f;
        #pragma unroll
        for (int k = 0; k < CHUNKS; ++k) {
            const int p0 = 4 * (tid + k * BLOCK);
            float prev = __shfl_up(v[k].w, 1, 64);
            if (lane == 0)
                prev = (wave > 0) ? bnd[wave - 1][k]
                                  : (k > 0 ? bnd[BLOCK / 64 - 1][k - 1] : 0.0f);
            if (p0 >= 1 && p0     < count) s += fabsf(v[k].x - prev);
            if (p0 + 1 < count)            s += fabsf(v[k].y - v[k].x);
            if (p0 + 2 < count)            s += fabsf(v[k].z - v[k].y);
            if (p0 + 3 < count)            s += fabsf(v[k].w - v[k].z);
        }
    }

    #pragma unroll
    for (int off = 32; off > 0; off >>= 1) s += __shfl_down(s, off, 64);
    if (lane == 0) sred[wave] = s;
    __syncthreads();
    if (tid == 0) {
        const float tot = sred[0] + sred[1] + sred[2] + sred[3];
        ws[row] = tot / ((float)count * (float)BSZ);
    }
}

__global__ __launch_bounds__(BLOCK) void consec_loss_finish(
    const float* __restrict__ ws, float* __restrict__ out) {
    const int tid = threadIdx.x;
    const float4* w4 = reinterpret_cast<const float4*>(ws);
    float s = 0.0f;
    #pragma unroll
    for (int k = 0; k < BSZ / 4 / BLOCK; ++k) {  // 4 float4 per thread
        float4 f = w4[tid + k * BLOCK];
        s += (f.x + f.y) + (f.z + f.w);
    }
    #pragma unroll
    for (int off = 32; off > 0; off >>= 1) s += __shfl_down(s, off, 64);
    __shared__ float sred[BLOCK / 64];
    const int wave = tid >> 6, lane = tid & 63;
    if (lane == 0) sred[wave] = s;
    __syncthreads();
    if (tid == 0) out[0] = sred[0] + sred[1] + sred[2] + sred[3];
}

extern "C" void kernel_launch(void* const* d_in, const int* in_sizes, int n_in,
                              void* d_out, int out_size, void* d_ws, size_t ws_size,
                              hipStream_t stream) {
    const float* x = (const float*)d_in[0];
    float* ws  = (float*)d_ws;   // 4096 per-row partials; every slot written every call
    float* out = (float*)d_out;
    consec_loss_kernel<<<dim3(BSZ), dim3(BLOCK), 0, stream>>>(x, ws);
    consec_loss_finish<<<dim3(1), dim3(BLOCK), 0, stream>>>(ws, out);
}

// Round 5
// 24.706 us; speedup vs baseline: 2.7585x; 1.1335x over previous
//
#include <hip/hip_runtime.h>

// ConsecutiveLoss: x is (4096, 8192) fp32.
// real_length[i] = nnz(row i); per_row = sum_{pos=1}^{rl-1} |x[i,pos]-x[i,pos-1]| / rl
// out = sum_{i>=1} per_row[i] / bsz
typedef float f4 __attribute__((ext_vector_type(4)));

constexpr int SEQ    = 8192;
constexpr int BSZ    = 4096;
constexpr int BLOCK  = 256;
constexpr int CHUNKS = SEQ / 4 / BLOCK;  // 8 float4 per thread
constexpr int NWAVE  = BLOCK / 64;

__global__ __launch_bounds__(BLOCK) void consec_loss_kernel(
    const float* __restrict__ x, float* __restrict__ ws) {
    const int tid = threadIdx.x;
    const int row = blockIdx.x;

    if (row == 0) {                      // row 0 is skipped by the reference
        if (tid == 0) ws[0] = 0.0f;
        return;
    }

    const f4* x4 = reinterpret_cast<const f4*>(x) + (size_t)row * (SEQ / 4);
    const int wave = tid >> 6, lane = tid & 63;

    __shared__ float bnd[NWAVE][CHUNKS];  // each wave's lane-63 v[k].w
    __shared__ int   cred[NWAVE];
    __shared__ float sred[NWAVE];

    // ---- phase 1: issue ALL loads first (max MLP), non-temporal (zero reuse) ----
    f4 v[CHUNKS];
    #pragma unroll
    for (int k = 0; k < CHUNKS; ++k)
        v[k] = __builtin_nontemporal_load(x4 + tid + k * BLOCK);

    // ---- phase 2: speculative unmasked diffs + running min|x| (zero detection) ----
    // No count arithmetic here: 4 v_min (abs is a free modifier) per chunk replaces
    // 4 vcc-writing compares + scalar popcount chain.
    float s  = 0.0f;
    float mn = 1.0f;                      // ==0 iff this lane saw a zero element
    #pragma unroll
    for (int k = 0; k < CHUNKS; ++k) {
        if (lane == 63) bnd[wave][k] = v[k].w;   // wave-boundary carry
        mn = fminf(mn, fminf(fminf(fabsf(v[k].x), fabsf(v[k].y)),
                             fminf(fabsf(v[k].z), fabsf(v[k].w))));
        const float prev = __shfl_up(v[k].w, 1, 64);
        if (lane > 0) s += fabsf(v[k].x - prev); // lanes 1..63 carry in-wave
        s += fabsf(v[k].y - v[k].x);
        s += fabsf(v[k].z - v[k].y);
        s += fabsf(v[k].w - v[k].z);
    }
    if (lane == 0) cred[wave] = __any(mn == 0.0f) ? 1 : 0;
    __syncthreads();
    const bool anyz = (cred[0] | cred[1] | cred[2] | cred[3]) != 0;

    float inv_div;
    if (!anyz) {
        // dense row (always, for Gaussian data): count == SEQ; speculative sum is
        // exact except the wave-boundary diffs only lane 0 couldn't compute.
        if (lane == 0) {
            #pragma unroll
            for (int k = 0; k < CHUNKS; ++k) {
                if (wave > 0)   s += fabsf(v[k].x - bnd[wave - 1][k]);
                else if (k > 0) s += fabsf(v[k].x - bnd[NWAVE - 1][k - 1]);
                // wave 0, chunk 0: position 0 has no predecessor
            }
        }
        inv_div = 1.0f / ((float)SEQ * (float)BSZ);
    } else {
        // slow path (row contains zeros): exact count + masked recompute, all
        // from register-resident v[]. Never taken on the bench data but correct.
        __syncthreads();                  // cred reads above must complete before rewrite
        int cnt = 0;
        #pragma unroll
        for (int k = 0; k < CHUNKS; ++k) {
            cnt += (v[k].x != 0.0f) + (v[k].y != 0.0f)
                 + (v[k].z != 0.0f) + (v[k].w != 0.0f);
        }
        #pragma unroll
        for (int off = 32; off > 0; off >>= 1) cnt += __shfl_down(cnt, off, 64);
        if (lane == 0) cred[wave] = cnt;
        __syncthreads();
        const int count = cred[0] + cred[1] + cred[2] + cred[3];

        s = 0.0f;
        #pragma unroll
        for (int k = 0; k < CHUNKS; ++k) {
            const int p0 = 4 * (tid + k * BLOCK);
            float prev = __shfl_up(v[k].w, 1, 64);
            if (lane == 0)
                prev = (wave > 0) ? bnd[wave - 1][k]
                                  : (k > 0 ? bnd[NWAVE - 1][k - 1] : 0.0f);
            if (p0 >= 1 && p0     < count) s += fabsf(v[k].x - prev);
            if (p0 + 1 < count)            s += fabsf(v[k].y - v[k].x);
            if (p0 + 2 < count)            s += fabsf(v[k].z - v[k].y);
            if (p0 + 3 < count)            s += fabsf(v[k].w - v[k].z);
        }
        inv_div = 1.0f / ((float)count * (float)BSZ);
    }

    #pragma unroll
    for (int off = 32; off > 0; off >>= 1) s += __shfl_down(s, off, 64);
    if (lane == 0) sred[wave] = s;
    __syncthreads();
    if (tid == 0) {
        const float tot = sred[0] + sred[1] + sred[2] + sred[3];
        ws[row] = tot * inv_div;
    }
}

__global__ __launch_bounds__(BLOCK) void consec_loss_finish(
    const float* __restrict__ ws, float* __restrict__ out) {
    const int tid = threadIdx.x;
    const f4* w4 = reinterpret_cast<const f4*>(ws);
    float s = 0.0f;
    #pragma unroll
    for (int k = 0; k < BSZ / 4 / BLOCK; ++k) {  // 4 float4 per thread
        f4 f = w4[tid + k * BLOCK];
        s += (f.x + f.y) + (f.z + f.w);
    }
    #pragma unroll
    for (int off = 32; off > 0; off >>= 1) s += __shfl_down(s, off, 64);
    __shared__ float sred[BLOCK / 64];
    const int wave = tid >> 6, lane = tid & 63;
    if (lane == 0) sred[wave] = s;
    __syncthreads();
    if (tid == 0) out[0] = sred[0] + sred[1] + sred[2] + sred[3];
}

extern "C" void kernel_launch(void* const* d_in, const int* in_sizes, int n_in,
                              void* d_out, int out_size, void* d_ws, size_t ws_size,
                              hipStream_t stream) {
    const float* x = (const float*)d_in[0];
    float* ws  = (float*)d_ws;   // 4096 per-row partials; every slot written every call
    float* out = (float*)d_out;
    consec_loss_kernel<<<dim3(BSZ), dim3(BLOCK), 0, stream>>>(x, ws);
    consec_loss_finish<<<dim3(1), dim3(BLOCK), 0, stream>>>(ws, out);
}